// Round 3
// baseline (497.047 us; speedup 1.0000x reference)
//
#include <hip/hip_runtime.h>
#include <hip/hip_bf16.h>

#define NTOK 98
#define DIM 192
#define HEADS 6
#define SCALE 0.17677669529663687f

using shortx8 = __attribute__((ext_vector_type(8))) short;
using floatx4 = __attribute__((ext_vector_type(4))) float;

static __device__ __forceinline__ unsigned short f2bf(float f) {
    unsigned u = __float_as_uint(f);
    u += 0x7FFFu + ((u >> 16) & 1u);   // RNE
    return (unsigned short)(u >> 16);
}

static __device__ __forceinline__ shortx8 pack8(const float* p, float scale) {
    float4 a = *(const float4*)p;
    float4 b = *(const float4*)(p + 4);
    shortx8 t;
    t[0] = (short)f2bf(a.x * scale); t[1] = (short)f2bf(a.y * scale);
    t[2] = (short)f2bf(a.z * scale); t[3] = (short)f2bf(a.w * scale);
    t[4] = (short)f2bf(b.x * scale); t[5] = (short)f2bf(b.y * scale);
    t[6] = (short)f2bf(b.z * scale); t[7] = (short)f2bf(b.w * scale);
    return t;
}

// ---------------- prep: bias gather + weight bf16 fragment-linear layouts ----------------
__global__ void prep_kernel(const float* __restrict__ rpb, const int* __restrict__ relidx,
                            const float* __restrict__ kvw, const float* __restrict__ pw,
                            float* __restrict__ biasF, unsigned short* __restrict__ kvB,
                            unsigned short* __restrict__ pB) {
    int e = blockIdx.x * 256 + threadIdx.x;
    if (e < HEADS * NTOK * NTOK) {
        int h = e / (NTOK * NTOK), ij = e % (NTOK * NTOK);
        biasF[e] = rpb[relidx[ij] * HEADS + h];
    }
    if (e < 73728) {
        int jj = e & 7, lane = (e >> 3) & 63, t = e >> 9;
        int NT = t % 24, ks = t / 24;
        int c = ks * 32 + (lane >> 4) * 8 + jj;
        int n = NT * 16 + (lane & 15);
        kvB[e] = f2bf(kvw[c * 384 + n]);
    }
    if (e < 36864) {
        int jj = e & 7, lane = (e >> 3) & 63, t = e >> 9;
        int NT = t % 12, ks = t / 12;
        int c = ks * 32 + (lane >> 4) * 8 + jj;
        int n = NT * 16 + (lane & 15);
        pB[e] = f2bf(pw[c * 192 + n]);
    }
}

// ------------- fused: kv-GEMM + QK + softmax + PV + proj, one block per window -------------
// 14 waves = 7 mtiles x 2 head-slots. 3 passes of 2 heads (wave p owns head 2a+p).
// PA and OA are per-wave-private transpose scratch -> no barriers inside the head pipeline.
__global__ __launch_bounds__(896, 4) void fused_kernel(
    const float* __restrict__ skip, const float* __restrict__ xup,
    const float* __restrict__ mask, const float* __restrict__ kv_b,
    const float* __restrict__ biasF, const unsigned short* __restrict__ kvB,
    const unsigned short* __restrict__ pB, const float* __restrict__ pb,
    float* __restrict__ out) {

    __shared__ unsigned short kB[2 * 7 * 512];      // k B-frags, 2 heads   (14336 B)
    __shared__ unsigned short vB[2 * 2 * 4 * 512];  // v B-frags, 2 heads   (16384 B)
    __shared__ unsigned short PA[14 * 4 * 512];     // P A-frags, per-wave  (57344 B)
    __shared__ unsigned short OA[7 * 6 * 512];      // O A-frags, per-mtile (43008 B)

    const int tid    = threadIdx.x;
    const int waveid = tid >> 6;      // 0..13
    const int lane   = tid & 63;
    const int l15    = lane & 15;
    const int quad   = lane >> 4;
    const int w      = waveid >> 1;   // mtile 0..6
    const int p      = waveid & 1;    // head slot within pass
    const int win    = blockIdx.x;

    // zero PA pad (j=112..127 of ks=3) — wave-private, written once, never overwritten
    {
        unsigned long long* z = (unsigned long long*)&PA[waveid * 2048 + 3 * 512 + 256];
        z[lane] = 0ull;                               // 64 lanes x 8B = 512 B
    }
    // zero vB ks=3 slabs (token pad 98..127) by waveid 13 — the SAME wave that later
    // writes the m=96,97 v-values there, so program order guarantees zeros-then-values.
    if (waveid == 13) {
        #pragma unroll
        for (int s = 0; s < 4; ++s) {
            uint4* z = (uint4*)&vB[(s * 4 + 3) * 512];
            z[lane] = make_uint4(0, 0, 0, 0);         // 64 x 16B = full 1024 B slab
        }
    }

    const int mA  = w * 16 + l15;
    const int mAc = mA < NTOK ? mA : NTOK - 1;        // clamp pad query rows

    // skip A-frags: loaded ONCE, persistent across all 3 kv passes
    shortx8 afr[6];
    {
        const float* sr = skip + ((size_t)win * NTOK + mAc) * DIM + quad * 8;
        #pragma unroll
        for (int ks = 0; ks < 6; ++ks) afr[ks] = pack8(sr + ks * 32, 1.0f);
    }

    const float* mw   = mask + (size_t)(win & 63) * NTOK * NTOK;
    float*       base = out + (size_t)win * NTOK * DIM;

    for (int a = 0; a < 3; ++a) {
        if (a) __syncthreads();   // protect kB/vB from overwrite while prior readers active

        // ---- phase1: kv slice for heads {2a, 2a+1}; p=0 -> k tiles, p=1 -> v tiles ----
        #pragma unroll
        for (int t = 0; t < 4; ++t) {
            const int NT  = (p ? 12 : 0) + 4 * a + t;   // global kv_w col tile
            const int col = NT * 16 + l15;
            const float cb = kv_b[col];
            floatx4 acc = {cb, cb, cb, cb};
            #pragma unroll
            for (int ks = 0; ks < 6; ++ks) {
                shortx8 bf = *(const shortx8*)(kvB + ((size_t)((ks * 24 + NT) * 64 + lane)) * 8);
                acc = __builtin_amdgcn_mfma_f32_16x16x32_bf16(afr[ks], bf, acc, 0, 0, 0);
            }
            const int cl = t * 16 + l15;               // col within the 2-head group (0..63)
            const int hh = cl >> 5, dh = cl & 31;
            if (!p) {   // k -> B-frag layout for QK (pad rows written as finite dupes)
                const int bpos = (hh * 7 + w) * 512 + (dh & 7);
                const int lphi = ((dh >> 3) & 3) << 4;
                #pragma unroll
                for (int r = 0; r < 4; ++r)
                    kB[bpos + ((quad * 4 + r) | lphi) * 8] = f2bf(acc[r]);
            } else {    // v -> B-frag layout for PV (token on K axis; pads stay zero)
                const int ntv = dh >> 4;
                #pragma unroll
                for (int r = 0; r < 4; ++r) {
                    int j = w * 16 + quad * 4 + r;
                    if (j < NTOK) {
                        int lp = (dh & 15) | (((j >> 3) & 3) << 4);
                        vB[((hh * 2 + ntv) * 4 + (j >> 5)) * 512 + lp * 8 + (j & 7)] = f2bf(acc[r]);
                    }
                }
            }
        }
        __syncthreads();   // publish kB/vB

        // ---- head h = 2a + p : barrier-free pipeline ----
        const int h = 2 * a + p;
        shortx8 qf = pack8(xup + ((size_t)win * NTOK + mAc) * DIM + h * 32 + quad * 8, SCALE);

        floatx4 S[7];
        const float* bh = biasF + h * NTOK * NTOK;
        #pragma unroll
        for (int nt = 0; nt < 7; ++nt) {
            const int j = nt * 16 + l15;
            #pragma unroll
            for (int r = 0; r < 4; ++r) {
                int i = w * 16 + quad * 4 + r;
                int ic = i < NTOK ? i : NTOK - 1;
                S[nt][r] = (j < NTOK) ? (bh[ic * NTOK + j] + mw[ic * NTOK + j]) : -1e30f;
            }
        }
        #pragma unroll
        for (int nt = 0; nt < 7; ++nt) {
            shortx8 bk = *(const shortx8*)&kB[(p * 7 + nt) * 512 + lane * 8];
            S[nt] = __builtin_amdgcn_mfma_f32_16x16x32_bf16(qf, bk, S[nt], 0, 0, 0);
        }
        float inv[4];
        #pragma unroll
        for (int r = 0; r < 4; ++r) {
            float mx = S[0][r];
            #pragma unroll
            for (int nt = 1; nt < 7; ++nt) mx = fmaxf(mx, S[nt][r]);
            mx = fmaxf(mx, __shfl_xor(mx, 1));
            mx = fmaxf(mx, __shfl_xor(mx, 2));
            mx = fmaxf(mx, __shfl_xor(mx, 4));
            mx = fmaxf(mx, __shfl_xor(mx, 8));
            float sm = 0.f;
            #pragma unroll
            for (int nt = 0; nt < 7; ++nt) { float ev = __expf(S[nt][r] - mx); S[nt][r] = ev; sm += ev; }
            sm += __shfl_xor(sm, 1);
            sm += __shfl_xor(sm, 2);
            sm += __shfl_xor(sm, 4);
            sm += __shfl_xor(sm, 8);
            inv[r] = 1.0f / sm;
        }
        // P -> private PA slab (A-frag layout); same-wave RAW handled by lgkmcnt
        unsigned short* PAw = PA + waveid * 2048;
        #pragma unroll
        for (int nt = 0; nt < 7; ++nt) {
            const int j = nt * 16 + l15;
            const int ks = nt >> 1;
            const int lphi = ((j >> 3) & 3) << 4;
            #pragma unroll
            for (int r = 0; r < 4; ++r)
                PAw[ks * 512 + ((quad * 4 + r) | lphi) * 8 + (j & 7)] = f2bf(S[nt][r] * inv[r]);
        }
        shortx8 pa[4];
        #pragma unroll
        for (int ks = 0; ks < 4; ++ks)
            pa[ks] = *(const shortx8*)&PAw[ks * 512 + lane * 8];
        #pragma unroll
        for (int nt = 0; nt < 2; ++nt) {
            floatx4 o = {0.f, 0.f, 0.f, 0.f};
            #pragma unroll
            for (int ks = 0; ks < 4; ++ks) {
                shortx8 vb = *(const shortx8*)&vB[((p * 2 + nt) * 4 + ks) * 512 + lane * 8];
                o = __builtin_amdgcn_mfma_f32_16x16x32_bf16(pa[ks], vb, o, 0, 0, 0);
            }
            // O -> OA in proj-A-frag layout (wave w owns slab w: no barrier; pads = finite dupes)
            const int kbase = h * 32 + nt * 16 + l15;
            const int lphi  = ((kbase >> 3) & 3) << 4;
            #pragma unroll
            for (int r = 0; r < 4; ++r) {
                int m = quad * 4 + r;
                OA[(w * 6 + h) * 512 + (m | lphi) * 8 + (kbase & 7)] = f2bf(o[r]);
            }
        }
    }
    __syncthreads();   // publish OA (proj A-frags cross the p halves)

    // ---- proj: out = O @ proj_w + proj_b ----
    shortx8 ao[6];
    #pragma unroll
    for (int ks = 0; ks < 6; ++ks)
        ao[ks] = *(const shortx8*)&OA[(w * 6 + ks) * 512 + lane * 8];
    #pragma unroll
    for (int t = 0; t < 6; ++t) {
        const int nt = p * 6 + t;
        const int n  = nt * 16 + l15;
        const float bb = pb[n];
        floatx4 acc = {bb, bb, bb, bb};
        #pragma unroll
        for (int ks = 0; ks < 6; ++ks) {
            shortx8 bf = *(const shortx8*)(pB + ((size_t)((ks * 12 + nt) * 64 + lane)) * 8);
            acc = __builtin_amdgcn_mfma_f32_16x16x32_bf16(ao[ks], bf, acc, 0, 0, 0);
        }
        #pragma unroll
        for (int r = 0; r < 4; ++r) {
            int m = w * 16 + quad * 4 + r;
            if (m < NTOK) base[m * DIM + n] = acc[r];
        }
    }
}

extern "C" void kernel_launch(void* const* d_in, const int* in_sizes, int n_in,
                              void* d_out, int out_size, void* d_ws, size_t ws_size,
                              hipStream_t stream) {
    const float* skip   = (const float*)d_in[0];
    const float* x_up   = (const float*)d_in[1];
    const float* mask   = (const float*)d_in[2];
    const float* kv_w   = (const float*)d_in[3];
    const float* kv_b   = (const float*)d_in[4];
    const float* proj_w = (const float*)d_in[5];
    const float* proj_b = (const float*)d_in[6];
    const float* rpb    = (const float*)d_in[7];
    const int*   relidx = (const int*)d_in[8];
    float* out = (float*)d_out;

    float*          biasF = (float*)d_ws;                               // 230496 B
    unsigned short* kvB   = (unsigned short*)((char*)d_ws + 230496);    // 147456 B
    unsigned short* pB    = (unsigned short*)((char*)d_ws + 377952);    //  73728 B

    prep_kernel<<<288, 256, 0, stream>>>(rpb, relidx, kv_w, proj_w, biasF, kvB, pB);
    fused_kernel<<<1024, 896, 0, stream>>>(skip, x_up, mask, kv_b, biasF, kvB, pB, proj_b, out);
}